// Round 4
// baseline (404.295 us; speedup 1.0000x reference)
//
#include <hip/hip_runtime.h>

// ---------------------------------------------------------------------------
// FDA_Module_21500606283969: out = x + MLP(LN(x))
// R3: fast tanh-GELU; XCD-aware block swizzle; GEMM4 residual from xb (bf16).
// R4: swapped-operand MFMA epilogue (acc[nt][mt] = mfma(b,a,acc) -> C^T frag):
//     lane holds 4 consecutive output cols -> packed dwordx2 bf16 stores /
//     float4 stores+loads, rs/mu loaded 4x not 16x.
// R5: BK=64 K-loop: halves the per-K-step {stage, vmcnt(0)-drain, barrier}
//     events. XOR-swizzled LDS (granule ^= row&7) via linear LDS dest +
//     inverse-swizzled GLOBAL source + swizzled ds_read keeps frag reads at
//     the 8-access/bank structural minimum. 32KB LDS/block.
// R6: K and N are template constants -> full K-loop unroll; staging byte
//     offsets fold into global_load_lds' 13-bit signed immediate, deleting
//     per-iteration address VALU; constexpr epilogue strides.
// R7: no code change — resubmit of the R4+R5+R6 stack after 4 infra
//     failures (stack has never executed; adding a 4th unverified change
//     would make the eventual first measurement unattributable).
// ---------------------------------------------------------------------------

typedef short short8 __attribute__((ext_vector_type(8)));
typedef float floatx4 __attribute__((ext_vector_type(4)));
typedef unsigned short ushort4v __attribute__((ext_vector_type(4)));
typedef unsigned int uint2v __attribute__((ext_vector_type(2)));

__device__ __forceinline__ unsigned short f2bf(float f) {
    union { float f; unsigned int u; } a; a.f = f;
    unsigned int u = a.u;
    return (unsigned short)((u + 0x7FFFu + ((u >> 16) & 1u)) >> 16);
}

__device__ __forceinline__ float bf2f(unsigned short h) {
    union { unsigned int u; float f; } a; a.u = ((unsigned int)h) << 16;
    return a.f;
}

__device__ __forceinline__ unsigned int pkbf(float a, float b) {
    return (unsigned int)f2bf(a) | ((unsigned int)f2bf(b) << 16);
}

// tanh-approx GELU; |err vs exact erf-GELU| <~ 1e-4, below bf16 rounding.
__device__ __forceinline__ float gelu_fast(float v) {
    float u = 0.7978845608f * v * (1.0f + 0.044715f * v * v);
    float e = __builtin_amdgcn_exp2f(u * 2.885390082f);      // exp(2u)
    float t = 1.0f - 2.0f * __builtin_amdgcn_rcpf(1.0f + e); // tanh(u)
    return 0.5f * v * (1.0f + t);
}

// async global->LDS, 16B per lane; LDS dst = wave-uniform base + lane*16
__device__ __forceinline__ void gl_lds16(const unsigned short* g, unsigned short* l) {
    __builtin_amdgcn_global_load_lds(
        (const __attribute__((address_space(1))) void*)g,
        (__attribute__((address_space(3))) void*)l, 16, 0, 0);
}

// ---- fused weight transpose+convert for all four weights (one launch)
// Wt[n*K+k] = bf16(W[k*N+n] * (scale?scale[k]:1))
__global__ __launch_bounds__(256) void conv_all_kernel(
    const float* __restrict__ W1, const float* __restrict__ W2,
    const float* __restrict__ W3, const float* __restrict__ W4,
    const float* __restrict__ gamma,
    unsigned short* __restrict__ Wt1, unsigned short* __restrict__ Wt2,
    unsigned short* __restrict__ Wt3, unsigned short* __restrict__ Wt4) {
    int b = blockIdx.x;
    const float* W; unsigned short* Wt; int K, N; const float* sc = nullptr;
    if (b < 2048)      { W = W1; Wt = Wt1; K = 1024; N = 512;  sc = gamma; }
    else if (b < 3072) { W = W2; Wt = Wt2; K = 512;  N = 512;  b -= 2048; }
    else if (b < 3584) { W = W3; Wt = Wt3; K = 512;  N = 256;  b -= 3072; }
    else               { W = W4; Wt = Wt4; K = 256;  N = 1024; b -= 3584; }
    int t = b * 256 + threadIdx.x;          // t = k*N + n (coalesced read)
    int sh = 31 - __clz(N);                 // N is a power of two
    int k = t >> sh, n = t & (N - 1);
    float v = W[t];
    if (sc) v *= sc[k];
    Wt[(size_t)n * K + k] = f2bf(v);
}

// ---- u1[n]=0 ; c1[n]=b1[n]  (seed for atomic accumulation)
__global__ __launch_bounds__(256) void u1c1_init_kernel(
    const float* __restrict__ b1, float* __restrict__ u1, float* __restrict__ c1,
    int N) {
    int n = blockIdx.x * 256 + threadIdx.x;
    if (n >= N) return;
    u1[n] = 0.f;
    c1[n] = b1[n];
}

// ---- partial u1/c1: block b covers k in [b*16, b*16+16), thread -> cols n, n+256
__global__ __launch_bounds__(256) void u1c1_kernel(
    const float* __restrict__ W1, const float* __restrict__ gamma,
    const float* __restrict__ beta, float* __restrict__ u1,
    float* __restrict__ c1) {
    const int N = 512;
    __shared__ float gs[16], bs[16];
    int n = threadIdx.x;
    int k0 = blockIdx.x * 16;
    if (n < 16) { gs[n] = gamma[k0 + n]; bs[n] = beta[k0 + n]; }
    __syncthreads();
    float ua = 0.f, ca = 0.f, ub = 0.f, cb = 0.f;
#pragma unroll
    for (int i = 0; i < 16; i++) {
        float w0 = W1[(size_t)(k0 + i) * N + n];
        float w1 = W1[(size_t)(k0 + i) * N + n + 256];
        ua += gs[i] * w0; ca += bs[i] * w0;
        ub += gs[i] * w1; cb += bs[i] * w1;
    }
    atomicAdd(&u1[n], ua);       atomicAdd(&c1[n], ca);
    atomicAdd(&u1[n + 256], ub); atomicAdd(&c1[n + 256], cb);
}

// ---- per-row LN stats (one wave per row, D=1024); optionally emit xb=bf16(x)
__global__ __launch_bounds__(256) void ln_stats_kernel(
    const float* __restrict__ x, float* __restrict__ mu, float* __restrict__ rs,
    unsigned short* __restrict__ xb) {
    const int D = 1024;
    int row = blockIdx.x * 4 + (threadIdx.x >> 6);
    int lane = threadIdx.x & 63;
    const float4* xr = (const float4*)(x + (size_t)row * D);
    float s = 0.f, ss = 0.f;
#pragma unroll
    for (int i = 0; i < 4; i++) {
        float4 v = xr[lane + 64 * i];
        s  += v.x + v.y + v.z + v.w;
        ss += v.x * v.x + v.y * v.y + v.z * v.z + v.w * v.w;
        if (xb) {
            ushort4v o;
            o.x = f2bf(v.x); o.y = f2bf(v.y); o.z = f2bf(v.z); o.w = f2bf(v.w);
            *(ushort4v*)(xb + (size_t)row * D + 4 * (lane + 64 * i)) = o;
        }
    }
#pragma unroll
    for (int off = 32; off; off >>= 1) {
        s  += __shfl_xor(s, off);
        ss += __shfl_xor(ss, off);
    }
    if (lane == 0) {
        float m = s * (1.0f / 1024.0f);
        mu[row] = m;
        rs[row] = rsqrtf(ss * (1.0f / 1024.0f) - m * m + 1e-5f);
    }
}

// ---- GEMM: C[M,N] = A[M,K] * Bt[N,K]^T, 128x128 tile, BK=64, 256 thr / 4 waves
// XCD swizzle: same-A-panel n-blocks consecutive on one XCD for L2 A-reuse.
// LDS tiles [128][64] bf16, granule-swizzled: phys granule p of row r holds
// logical granule p^(r&7); linear LDS dest + inverse-swizzled GLOBAL source.
// MFMA operands SWAPPED (acc[nt][mt] = mfma(b, a, acc)) -> C^T fragment:
// lane holds row = l16 fixed, 4 consecutive cols per reg quad.
// EPMODE 0: LN-corrected + gelu -> bf16     EPMODE 1: +bias, gelu -> bf16
// EPMODE 2: +bias, +resid(fp32) -> fp32     EPMODE 3: +bias, +resid(bf16) -> fp32
template <int EPMODE, bool AF32, int NBN, int NT, int KT>
__global__ __launch_bounds__(256) void gemm_kernel(
    const void* __restrict__ Aptr, const unsigned short* __restrict__ Bt,
    void* __restrict__ Out,
    const float* __restrict__ bias,   // EP0: c1
    const float* __restrict__ u1,     // EP0 only
    const float* __restrict__ mu,     // EP0 only
    const float* __restrict__ rs,     // EP0 only
    const void* __restrict__ resid)   // EP2/EP3 only
{
    constexpr int BM = 128, BN = 128, BK = 64;
    constexpr int N = NT, K = KT;
    __shared__ unsigned short As[BM][BK];   // 16 KB
    __shared__ unsigned short Bs[BN][BK];   // 16 KB

    const int tid  = threadIdx.x;
    const int wave = tid >> 6;
    const int lane = tid & 63;
    const int q    = lane >> 4;   // quad 0..3
    const int l16  = lane & 15;
    const int wm   = wave & 1;    // wave row-half
    const int wn   = wave >> 1;   // wave col-half

    // XCD-aware swizzle (grid size is a multiple of 8 for all call sites)
    const int id   = blockIdx.x;
    const int xcd  = id & 7;
    const int slot = id >> 3;
    const int m0   = (xcd + 8 * (slot / NBN)) * BM;
    const int n0   = (slot % NBN) * BN;

    // staging geometry: thread tid covers 16B granule (sr, sc) of a 32-row
    // chunk; the inverse swizzle (sc ^ (sr&7)) is applied to the SOURCE col.
    const int sr  = tid >> 3;         // chunk-row 0..31
    const int sc  = tid & 7;          // physical granule 0..7
    const int sg  = sc ^ (sr & 7);    // logical (source) granule
    unsigned short* lA = &As[0][0] + (wave << 9);  // wave*1024 B
    unsigned short* lB = &Bs[0][0] + (wave << 9);
    const unsigned short* gb0 = Bt + (size_t)(n0 + sr) * K + sg * 8;
    const unsigned short* ga0 = nullptr;
    if (!AF32) ga0 = (const unsigned short*)Aptr + (size_t)(m0 + sr) * K + sg * 8;

    floatx4 acc[4][4] = {};   // acc[nt][mt] — C^T fragments

#pragma unroll
    for (int k0 = 0; k0 < K; k0 += BK) {
        if (AF32) {
            const float* A = (const float*)Aptr;
            int c = tid & 15, r0 = tid >> 4;   // c: float4 chunk 0..15, r0: 0..15
#pragma unroll
            for (int i = 0; i < 8; i++) {
                int r = r0 + 16 * i;
                float4 v = *(const float4*)(A + (size_t)(m0 + r) * K + k0 + c * 4);
                ushort4v o;
                o.x = f2bf(v.x); o.y = f2bf(v.y);
                o.z = f2bf(v.z); o.w = f2bf(v.w);
                // swizzled dest: row r, phys granule (c>>1)^(r&7), half c&1
                int idx = r * 64 + (((c >> 1) ^ (r & 7)) << 3) + ((c & 1) << 2);
                *(ushort4v*)(&As[0][0] + idx) = o;
            }
        } else {
#pragma unroll
            for (int c = 0; c < 4; c++)
                gl_lds16(ga0 + k0 + (size_t)(32 * c) * K, lA + c * 2048);
        }
#pragma unroll
        for (int c = 0; c < 4; c++)
            gl_lds16(gb0 + k0 + (size_t)(32 * c) * K, lB + c * 2048);
        __syncthreads();

#pragma unroll
        for (int kk = 0; kk < 2; kk++) {
            const int gsw = ((kk * 4 + q) ^ (l16 & 7)) * 8;  // swizzled granule
            short8 a[4], b[4];
#pragma unroll
            for (int mt = 0; mt < 4; mt++)
                a[mt] = *(const short8*)(&As[0][0] + (wm * 64 + mt * 16 + l16) * 64 + gsw);
#pragma unroll
            for (int nt = 0; nt < 4; nt++)
                b[nt] = *(const short8*)(&Bs[0][0] + (wn * 64 + nt * 16 + l16) * 64 + gsw);
#pragma unroll
            for (int nt = 0; nt < 4; nt++)
#pragma unroll
                for (int mt = 0; mt < 4; mt++)
                    acc[nt][mt] = __builtin_amdgcn_mfma_f32_16x16x32_bf16(
                        b[nt], a[mt], acc[nt][mt], 0, 0, 0);
        }
        __syncthreads();
    }

    // ---- epilogue (swapped C^T layout): for acc[nt][mt] reg r:
    //   n = n0 + wn*64 + nt*16 + q*4 + r   (4 consecutive cols)
    //   m = m0 + wm*64 + mt*16 + l16       (fixed per mt)
    float rs4[4], mu4[4];
    if constexpr (EPMODE == 0) {
#pragma unroll
        for (int mt = 0; mt < 4; mt++) {
            const int row = m0 + wm * 64 + mt * 16 + l16;
            rs4[mt] = rs[row];
            mu4[mt] = mu[row];
        }
    }
#pragma unroll
    for (int nt = 0; nt < 4; nt++) {
        const int nbase = n0 + wn * 64 + nt * 16 + q * 4;
        const float4 bv = *(const float4*)(bias + nbase);
        float4 uv = {0.f, 0.f, 0.f, 0.f};
        if constexpr (EPMODE == 0) uv = *(const float4*)(u1 + nbase);
#pragma unroll
        for (int mt = 0; mt < 4; mt++) {
            const int row = m0 + wm * 64 + mt * 16 + l16;
            const size_t off = (size_t)row * N + nbase;
            float v0 = acc[nt][mt][0], v1 = acc[nt][mt][1];
            float v2 = acc[nt][mt][2], v3 = acc[nt][mt][3];
            if constexpr (EPMODE == 0) {
                v0 = gelu_fast(rs4[mt] * (v0 - mu4[mt] * uv.x) + bv.x);
                v1 = gelu_fast(rs4[mt] * (v1 - mu4[mt] * uv.y) + bv.y);
                v2 = gelu_fast(rs4[mt] * (v2 - mu4[mt] * uv.z) + bv.z);
                v3 = gelu_fast(rs4[mt] * (v3 - mu4[mt] * uv.w) + bv.w);
                uint2v o; o.x = pkbf(v0, v1); o.y = pkbf(v2, v3);
                *(uint2v*)((unsigned short*)Out + off) = o;
            } else if constexpr (EPMODE == 1) {
                v0 = gelu_fast(v0 + bv.x);
                v1 = gelu_fast(v1 + bv.y);
                v2 = gelu_fast(v2 + bv.z);
                v3 = gelu_fast(v3 + bv.w);
                uint2v o; o.x = pkbf(v0, v1); o.y = pkbf(v2, v3);
                *(uint2v*)((unsigned short*)Out + off) = o;
            } else if constexpr (EPMODE == 2) {
                const float4 rv = *(const float4*)((const float*)resid + off);
                float4 o;
                o.x = v0 + bv.x + rv.x;
                o.y = v1 + bv.y + rv.y;
                o.z = v2 + bv.z + rv.z;
                o.w = v3 + bv.w + rv.w;
                *(float4*)((float*)Out + off) = o;
            } else {
                const ushort4v rv =
                    *(const ushort4v*)((const unsigned short*)resid + off);
                float4 o;
                o.x = v0 + bv.x + bf2f(rv.x);
                o.y = v1 + bv.y + bf2f(rv.y);
                o.z = v2 + bv.z + bf2f(rv.z);
                o.w = v3 + bv.w + bf2f(rv.w);
                *(float4*)((float*)Out + off) = o;
            }
        }
    }
}

extern "C" void kernel_launch(void* const* d_in, const int* in_sizes, int n_in,
                              void* d_out, int out_size, void* d_ws, size_t ws_size,
                              hipStream_t stream) {
    const float* x     = (const float*)d_in[0];
    const float* gamma = (const float*)d_in[1];
    const float* beta  = (const float*)d_in[2];
    const float* W1    = (const float*)d_in[3];
    const float* b1    = (const float*)d_in[4];
    const float* W2    = (const float*)d_in[5];
    const float* b2    = (const float*)d_in[6];
    const float* W3    = (const float*)d_in[7];
    const float* b3    = (const float*)d_in[8];
    const float* W4    = (const float*)d_in[9];
    const float* b4    = (const float*)d_in[10];
    float* out = (float*)d_out;

    const int D = 1024, H1 = 512, H2 = 512;
    const int M = in_sizes[0] / D;   // 32768

    // ---- workspace layout (bytes, all 256-aligned) -------------------------
    char* ws = (char*)d_ws;
    unsigned short* Wt1 = (unsigned short*)(ws + 0);          // 512x1024 bf16, gamma-folded
    unsigned short* Wt2 = (unsigned short*)(ws + 1048576);    // 512x512
    unsigned short* Wt3 = (unsigned short*)(ws + 1572864);    // 256x512
    unsigned short* Wt4 = (unsigned short*)(ws + 1835008);    // 1024x256
    float* u1           = (float*)(ws + 2359296);             // [512]
    float* c1           = (float*)(ws + 2361344);             // [512]
    float* muv          = (float*)(ws + 2363392);             // [M]
    float* rsv          = (float*)(ws + 2494464);             // [M]
    unsigned short* h1  = (unsigned short*)(ws + 2625536);    // M x 512 bf16 (32MB)
    unsigned short* h2  = (unsigned short*)(ws + 36179968);   // M x 512 bf16 (32MB)
    unsigned short* h3  = h1;                                 // alias: h1 dead after G2
    size_t base_end     = 36179968 + (size_t)M * H2 * 2;      // ~69.7MB
    // optional xb = bf16(x), M x 1024 (64MB): lds-direct A for GEMM1 + bf16 residual
    unsigned short* xb  = (unsigned short*)(ws + base_end);
    bool use_xb = (ws_size >= base_end + (size_t)M * D * 2);

    const int NBM = M / 128;   // 256

    // ---- weight prep (one fused launch) ------------------------------------
    conv_all_kernel<<<4608, 256, 0, stream>>>(W1, W2, W3, W4, gamma,
                                              Wt1, Wt2, Wt3, Wt4);
    u1c1_init_kernel<<<(H1 + 255) / 256, 256, 0, stream>>>(b1, u1, c1, H1);
    u1c1_kernel<<<D / 16, 256, 0, stream>>>(W1, gamma, beta, u1, c1);

    // ---- LN row stats (+ bf16 conversion of x) -----------------------------
    ln_stats_kernel<<<M / 4, 256, 0, stream>>>(x, muv, rsv, use_xb ? xb : nullptr);

    // ---- GEMM chain --------------------------------------------------------
    if (use_xb) {
        gemm_kernel<0, false, 4, 512, 1024><<<4 * NBM, 256, 0, stream>>>(
            xb, Wt1, h1, c1, u1, muv, rsv, nullptr);
    } else {
        gemm_kernel<0, true, 4, 512, 1024><<<4 * NBM, 256, 0, stream>>>(
            x,  Wt1, h1, c1, u1, muv, rsv, nullptr);
    }
    gemm_kernel<1, false, 4, 512, 512><<<4 * NBM, 256, 0, stream>>>(
        h1, Wt2, h2, b2, nullptr, nullptr, nullptr, nullptr);
    gemm_kernel<1, false, 2, 256, 512><<<2 * NBM, 256, 0, stream>>>(
        h2, Wt3, h3, b3, nullptr, nullptr, nullptr, nullptr);
    if (use_xb) {
        gemm_kernel<3, false, 8, 1024, 256><<<8 * NBM, 256, 0, stream>>>(
            h3, Wt4, out, b4, nullptr, nullptr, nullptr, xb);
    } else {
        gemm_kernel<2, false, 8, 1024, 256><<<8 * NBM, 256, 0, stream>>>(
            h3, Wt4, out, b4, nullptr, nullptr, nullptr, x);
    }
}

// Round 7
// 398.281 us; speedup vs baseline: 1.0151x; 1.0151x over previous
//
#include <hip/hip_runtime.h>

// ---------------------------------------------------------------------------
// FDA_Module_21500606283969: out = x + MLP(LN(x))
// R3: fast tanh-GELU; XCD-aware block swizzle; GEMM4 residual from xb (bf16).
// R4: swapped-operand MFMA epilogue -> C^T frag, packed stores.
// R5: BK=64 + XOR-granule-swizzled LDS on the 128^2 path.
// R6: constexpr K/N, full unroll on the 128^2 path.          [404.3 us meas.]
// R9: fixed-race 256x256 8-wave pipelined kernel for G1/G2 (K-split LDS
//     chunks, counted vmcnt(4), never-drain main loop). Full audit r10:
//     per-wave queue trace, cross-wave landing, WAR spacing, bank map,
//     tail parity — all verified.
// R10: no code change — resubmit (5th infra failure; kernel never executed;
//     holding the candidate stable keeps the first measurement attributable).
// ---------------------------------------------------------------------------

typedef short short8 __attribute__((ext_vector_type(8)));
typedef float floatx4 __attribute__((ext_vector_type(4)));
typedef unsigned short ushort4v __attribute__((ext_vector_type(4)));
typedef unsigned int uint2v __attribute__((ext_vector_type(2)));

__device__ __forceinline__ unsigned short f2bf(float f) {
    union { float f; unsigned int u; } a; a.f = f;
    unsigned int u = a.u;
    return (unsigned short)((u + 0x7FFFu + ((u >> 16) & 1u)) >> 16);
}

__device__ __forceinline__ float bf2f(unsigned short h) {
    union { unsigned int u; float f; } a; a.u = ((unsigned int)h) << 16;
    return a.f;
}

__device__ __forceinline__ unsigned int pkbf(float a, float b) {
    return (unsigned int)f2bf(a) | ((unsigned int)f2bf(b) << 16);
}

// tanh-approx GELU; |err vs exact erf-GELU| <~ 1e-4, below bf16 rounding.
__device__ __forceinline__ float gelu_fast(float v) {
    float u = 0.7978845608f * v * (1.0f + 0.044715f * v * v);
    float e = __builtin_amdgcn_exp2f(u * 2.885390082f);      // exp(2u)
    float t = 1.0f - 2.0f * __builtin_amdgcn_rcpf(1.0f + e); // tanh(u)
    return 0.5f * v * (1.0f + t);
}

// async global->LDS, 16B per lane; LDS dst = wave-uniform base + lane*16
__device__ __forceinline__ void gl_lds16(const unsigned short* g, unsigned short* l) {
    __builtin_amdgcn_global_load_lds(
        (const __attribute__((address_space(1))) void*)g,
        (__attribute__((address_space(3))) void*)l, 16, 0, 0);
}

#define BARX() asm volatile("s_barrier" ::: "memory")
#define VMW4() asm volatile("s_waitcnt vmcnt(4)" ::: "memory")
#define VMW0() asm volatile("s_waitcnt vmcnt(0)" ::: "memory")

// ---- fused weight transpose+convert for all four weights (one launch)
__global__ __launch_bounds__(256) void conv_all_kernel(
    const float* __restrict__ W1, const float* __restrict__ W2,
    const float* __restrict__ W3, const float* __restrict__ W4,
    const float* __restrict__ gamma,
    unsigned short* __restrict__ Wt1, unsigned short* __restrict__ Wt2,
    unsigned short* __restrict__ Wt3, unsigned short* __restrict__ Wt4) {
    int b = blockIdx.x;
    const float* W; unsigned short* Wt; int K, N; const float* sc = nullptr;
    if (b < 2048)      { W = W1; Wt = Wt1; K = 1024; N = 512;  sc = gamma; }
    else if (b < 3072) { W = W2; Wt = Wt2; K = 512;  N = 512;  b -= 2048; }
    else if (b < 3584) { W = W3; Wt = Wt3; K = 512;  N = 256;  b -= 3072; }
    else               { W = W4; Wt = Wt4; K = 256;  N = 1024; b -= 3584; }
    int t = b * 256 + threadIdx.x;
    int sh = 31 - __clz(N);
    int k = t >> sh, n = t & (N - 1);
    float v = W[t];
    if (sc) v *= sc[k];
    Wt[(size_t)n * K + k] = f2bf(v);
}

__global__ __launch_bounds__(256) void u1c1_init_kernel(
    const float* __restrict__ b1, float* __restrict__ u1, float* __restrict__ c1,
    int N) {
    int n = blockIdx.x * 256 + threadIdx.x;
    if (n >= N) return;
    u1[n] = 0.f;
    c1[n] = b1[n];
}

__global__ __launch_bounds__(256) void u1c1_kernel(
    const float* __restrict__ W1, const float* __restrict__ gamma,
    const float* __restrict__ beta, float* __restrict__ u1,
    float* __restrict__ c1) {
    const int N = 512;
    __shared__ float gs[16], bs[16];
    int n = threadIdx.x;
    int k0 = blockIdx.x * 16;
    if (n < 16) { gs[n] = gamma[k0 + n]; bs[n] = beta[k0 + n]; }
    __syncthreads();
    float ua = 0.f, ca = 0.f, ub = 0.f, cb = 0.f;
#pragma unroll
    for (int i = 0; i < 16; i++) {
        float w0 = W1[(size_t)(k0 + i) * N + n];
        float w1 = W1[(size_t)(k0 + i) * N + n + 256];
        ua += gs[i] * w0; ca += bs[i] * w0;
        ub += gs[i] * w1; cb += bs[i] * w1;
    }
    atomicAdd(&u1[n], ua);       atomicAdd(&c1[n], ca);
    atomicAdd(&u1[n + 256], ub); atomicAdd(&c1[n + 256], cb);
}

__global__ __launch_bounds__(256) void ln_stats_kernel(
    const float* __restrict__ x, float* __restrict__ mu, float* __restrict__ rs,
    unsigned short* __restrict__ xb) {
    const int D = 1024;
    int row = blockIdx.x * 4 + (threadIdx.x >> 6);
    int lane = threadIdx.x & 63;
    const float4* xr = (const float4*)(x + (size_t)row * D);
    float s = 0.f, ss = 0.f;
#pragma unroll
    for (int i = 0; i < 4; i++) {
        float4 v = xr[lane + 64 * i];
        s  += v.x + v.y + v.z + v.w;
        ss += v.x * v.x + v.y * v.y + v.z * v.z + v.w * v.w;
        if (xb) {
            ushort4v o;
            o.x = f2bf(v.x); o.y = f2bf(v.y); o.z = f2bf(v.z); o.w = f2bf(v.w);
            *(ushort4v*)(xb + (size_t)row * D + 4 * (lane + 64 * i)) = o;
        }
    }
#pragma unroll
    for (int off = 32; off; off >>= 1) {
        s  += __shfl_xor(s, off);
        ss += __shfl_xor(ss, off);
    }
    if (lane == 0) {
        float m = s * (1.0f / 1024.0f);
        mu[row] = m;
        rs[row] = rsqrtf(ss * (1.0f / 1024.0f) - m * m + 1e-5f);
    }
}

// ---------------------------------------------------------------------------
// 256x256 8-wave pipelined GEMM (G1/G2): C = A[M,K] * Bt[N,K]^T
// Waves 2(M)x4(N); per-wave out 128x64 (acc[8][4] 16x16 frags); BK=64.
// LDS [2 buf][A,B][2 khalf][256 rows x 32 k] bf16 (64B stride, conflict-free,
// no swizzle). Phases: p0=(kk0,ch0) p1=(kk0,ch1) p2=(kk1,ch0) p3=(kk1,ch1);
// p0/p1 read only kh0 chunks, p2/p3 only kh1. Stage next tile's
// {A-kh0,B-kh0,A-kh1,B-kh1} at p0..p3; vmcnt(4) at end of p1 and p3 only.
// ---------------------------------------------------------------------------
__device__ __forceinline__ void ldA8(const unsigned short* base, short8 (&a)[8]) {
#pragma unroll
    for (int mt = 0; mt < 8; mt++) a[mt] = *(const short8*)(base + mt * 512);
}
__device__ __forceinline__ void ldB2(const unsigned short* base, short8 (&bb)[2]) {
    bb[0] = *(const short8*)(base);
    bb[1] = *(const short8*)(base + 512);
}
template <int CH>
__device__ __forceinline__ void mm16(const short8 (&a)[8], const short8 (&bb)[2],
                                     floatx4 (&acc)[8][4]) {
    __builtin_amdgcn_s_setprio(1);
#pragma unroll
    for (int mt = 0; mt < 8; mt++)
#pragma unroll
        for (int nt = 0; nt < 2; nt++)
            acc[mt][CH * 2 + nt] = __builtin_amdgcn_mfma_f32_16x16x32_bf16(
                bb[nt], a[mt], acc[mt][CH * 2 + nt], 0, 0, 0);
    __builtin_amdgcn_s_setprio(0);
}

template <int KLEN, bool PF>
__device__ __forceinline__ void do_tile(
    const unsigned short* aK0, const unsigned short* aK1,
    const unsigned short* bK0, const unsigned short* bK1,
    unsigned short* stA0, unsigned short* stA1,
    unsigned short* stB0, unsigned short* stB1,
    const unsigned short* gAs, const unsigned short* gBs,
    short8 (&a)[8], short8 (&bb)[2], floatx4 (&acc)[8][4]) {
    // p0: kk0,ch0 | stage A-kh0(next)
    ldA8(aK0, a);
    ldB2(bK0, bb);
    if (PF) {
        gl_lds16(gAs, stA0);
        gl_lds16(gAs + (size_t)128 * KLEN, stA0 + 4096);
    }
    mm16<0>(a, bb, acc);
    BARX();
    // p1: kk0,ch1 | stage B-kh0(next) | wait: this tile's A/B-kh1 landed
    ldB2(bK0 + 1024, bb);
    if (PF) {
        gl_lds16(gBs, stB0);
        gl_lds16(gBs + (size_t)128 * KLEN, stB0 + 4096);
    }
    mm16<1>(a, bb, acc);
    if (PF) { VMW4(); } else { VMW0(); }
    BARX();
    // p2: kk1,ch0 | stage A-kh1(next)
    ldA8(aK1, a);
    ldB2(bK1, bb);
    if (PF) {
        gl_lds16(gAs + 32, stA1);
        gl_lds16(gAs + 32 + (size_t)128 * KLEN, stA1 + 4096);
    }
    mm16<0>(a, bb, acc);
    BARX();
    // p3: kk1,ch1 | stage B-kh1(next) | wait: next tile's A/B-kh0 landed
    ldB2(bK1 + 1024, bb);
    if (PF) {
        gl_lds16(gBs + 32, stB1);
        gl_lds16(gBs + 32 + (size_t)128 * KLEN, stB1 + 4096);
    }
    mm16<1>(a, bb, acc);
    if (PF) { VMW4(); }
    BARX();
}

template <int EPMODE, int NBN, int NT, int NOUT, int KLEN>
__global__ __launch_bounds__(512, 2) void gemm256_kernel(
    const unsigned short* __restrict__ A, const unsigned short* __restrict__ Bt,
    unsigned short* __restrict__ Out,
    const float* __restrict__ bias,   // EP0: c1 ; EP1: b
    const float* __restrict__ u1,     // EP0 only
    const float* __restrict__ mu,     // EP0 only
    const float* __restrict__ rs)     // EP0 only
{
    __shared__ unsigned short lds[2][2][2][8192];   // [buf][A/B][kh][256*32] = 128 KB

    const int tid  = threadIdx.x;
    const int wave = tid >> 6;
    const int lane = tid & 63;
    const int q    = lane >> 4;
    const int l16  = lane & 15;
    const int wm   = wave >> 2;   // 0..1 (M half, 128 rows)
    const int wn   = wave & 3;    // 0..3 (N quarter, 64 cols)

    // XCD-aware swizzle; grid = (M/256)*NBN, multiple of 8
    const int id   = blockIdx.x;
    const int xcd  = id & 7;
    const int slot = id >> 3;
    const int m0   = (xcd + 8 * (slot / NBN)) * 256;
    const int n0   = (slot % NBN) * 256;

    // staging: thread covers row tid>>2 (and +128 for 2nd load), granule tid&3
    const unsigned short* gAs = A  + (size_t)(m0 + (tid >> 2)) * KLEN + (tid & 3) * 8;
    const unsigned short* gBs = Bt + (size_t)(n0 + (tid >> 2)) * KLEN + (tid & 3) * 8;

    const int wo = wave << 9;   // wave-uniform staging offset (1024 B)
    unsigned short* stA00 = &lds[0][0][0][0] + wo;
    unsigned short* stA01 = &lds[0][0][1][0] + wo;
    unsigned short* stB00 = &lds[0][1][0][0] + wo;
    unsigned short* stB01 = &lds[0][1][1][0] + wo;
    unsigned short* stA10 = &lds[1][0][0][0] + wo;
    unsigned short* stA11 = &lds[1][0][1][0] + wo;
    unsigned short* stB10 = &lds[1][1][0][0] + wo;
    unsigned short* stB11 = &lds[1][1][1][0] + wo;

    const int aoff = (wm * 128 + l16) * 32 + q * 8;
    const int boff = (wn * 64 + l16) * 32 + q * 8;
    const unsigned short* aF00 = &lds[0][0][0][0] + aoff;
    const unsigned short* aF01 = &lds[0][0][1][0] + aoff;
    const unsigned short* bF00 = &lds[0][1][0][0] + boff;
    const unsigned short* bF01 = &lds[0][1][1][0] + boff;
    const unsigned short* aF10 = &lds[1][0][0][0] + aoff;
    const unsigned short* aF11 = &lds[1][0][1][0] + aoff;
    const unsigned short* bF10 = &lds[1][1][0][0] + boff;
    const unsigned short* bF11 = &lds[1][1][1][0] + boff;

    floatx4 acc[8][4] = {};
    short8 a[8], bb[2];

    // prologue: tile 0 -> buf0; issue order A-kh0, B-kh0, A-kh1, B-kh1
    gl_lds16(gAs,                           stA00);
    gl_lds16(gAs + (size_t)128 * KLEN,      stA00 + 4096);
    gl_lds16(gBs,                           stB00);
    gl_lds16(gBs + (size_t)128 * KLEN,      stB00 + 4096);
    gl_lds16(gAs + 32,                      stA01);
    gl_lds16(gAs + 32 + (size_t)128 * KLEN, stA01 + 4096);
    gl_lds16(gBs + 32,                      stB01);
    gl_lds16(gBs + 32 + (size_t)128 * KLEN, stB01 + 4096);
    VMW4();    // A-kh0, B-kh0 landed; kh1 pair still in flight
    BARX();
    gAs += 64; gBs += 64;

    for (int t = 0; t + 2 < NT; t += 2) {
        do_tile<KLEN, true>(aF00, aF01, bF00, bF01, stA10, stA11, stB10, stB11,
                            gAs, gBs, a, bb, acc);
        gAs += 64; gBs += 64;
        do_tile<KLEN, true>(aF10, aF11, bF10, bF11, stA00, stA01, stB00, stB01,
                            gAs, gBs, a, bb, acc);
        gAs += 64; gBs += 64;
    }
    do_tile<KLEN, true>(aF00, aF01, bF00, bF01, stA10, stA11, stB10, stB11,
                        gAs, gBs, a, bb, acc);
    do_tile<KLEN, false>(aF10, aF11, bF10, bF11, stA00, stA01, stB00, stB01,
                         gAs, gBs, a, bb, acc);

    // ---- epilogue (C^T frag): m = m0+wm*128+ma*16+l16 ; n = n0+wn*64+na*16+q*4+r
    float rs8[8], mu8[8];
    if constexpr (EPMODE == 0) {
#pragma unroll
        for (int ma = 0; ma < 8; ma++) {
            const int row = m0 + wm * 128 + ma * 16 + l16;
            rs8[ma] = rs[row];
            mu8[ma] = mu[row];
        }
    }
#pragma unroll
    for (int na = 0; na < 4; na++) {
        const int nb = n0 + wn * 64 + na * 16 + q * 4;
        const float4 bv = *(const float4*)(bias + nb);
        float4 uv = {0.f, 0.f, 0.f, 0.f};
        if constexpr (EPMODE == 0) uv = *(const float4*)(u1 + nb);
#pragma unroll
        for (int ma = 0; ma < 8; ma++) {
            const int row = m0 + wm * 128 + ma * 16 + l16;
            const size_t off = (size_t)row * NOUT + nb;
            float v0 = acc[ma][na][0], v1 = acc[ma][na][1];
            float v2 = acc[ma][na][2], v3 = acc[ma][na][3];
            if constexpr (EPMODE == 0) {
                v0 = gelu_fast(rs8[ma] * (v0 - mu8[ma] * uv.x) + bv.x);
                v1 = gelu_fast(rs8[ma] * (v1 - mu8[ma] * uv.y) + bv.y);
                v2 = gelu_fast(rs8[ma] * (v2 - mu8[ma] * uv.z) + bv.z);
                v3 = gelu_fast(rs8[ma] * (v3 - mu8[ma] * uv.w) + bv.w);
            } else {
                v0 = gelu_fast(v0 + bv.x);
                v1 = gelu_fast(v1 + bv.y);
                v2 = gelu_fast(v2 + bv.z);
                v3 = gelu_fast(v3 + bv.w);
            }
            uint2v o; o.x = pkbf(v0, v1); o.y = pkbf(v2, v3);
            *(uint2v*)(Out + off) = o;
        }
    }
}

// ---- 128x128 2-phase GEMM (G3/G4 + fallbacks), as measured at R7 ----------
template <int EPMODE, bool AF32, int NBN, int NT_, int KT>
__global__ __launch_bounds__(256) void gemm_kernel(
    const void* __restrict__ Aptr, const unsigned short* __restrict__ Bt,
    void* __restrict__ Out,
    const float* __restrict__ bias,
    const float* __restrict__ u1,
    const float* __restrict__ mu,
    const float* __restrict__ rs,
    const void* __restrict__ resid)
{
    constexpr int BM = 128, BN = 128, BK = 64;
    constexpr int N = NT_, K = KT;
    __shared__ unsigned short As[BM][BK];
    __shared__ unsigned short Bs[BN][BK];

    const int tid  = threadIdx.x;
    const int wave = tid >> 6;
    const int lane = tid & 63;
    const int q    = lane >> 4;
    const int l16  = lane & 15;
    const int wm   = wave & 1;
    const int wn   = wave >> 1;

    const int id   = blockIdx.x;
    const int xcd  = id & 7;
    const int slot = id >> 3;
    const int m0   = (xcd + 8 * (slot / NBN)) * BM;
    const int n0   = (slot % NBN) * BN;

    const int sr  = tid >> 3;
    const int sc  = tid & 7;
    const int sg  = sc ^ (sr & 7);
    unsigned short* lA = &As[0][0] + (wave << 9);
    unsigned short* lB = &Bs[0][0] + (wave << 9);
    const unsigned short* gb0 = Bt + (size_t)(n0 + sr) * K + sg * 8;
    const unsigned short* ga0 = nullptr;
    if (!AF32) ga0 = (const unsigned short*)Aptr + (size_t)(m0 + sr) * K + sg * 8;

    floatx4 acc[4][4] = {};

#pragma unroll
    for (int k0 = 0; k0 < K; k0 += BK) {
        if (AF32) {
            const float* A = (const float*)Aptr;
            int c = tid & 15, r0 = tid >> 4;
#pragma unroll
            for (int i = 0; i < 8; i++) {
                int r = r0 + 16 * i;
                float4 v = *(const float4*)(A + (size_t)(m0 + r) * K + k0 + c * 4);
                ushort4v o;
                o.x = f2bf(v.x); o.y = f2bf(v.y);
                o.z = f2bf(v.z); o.w = f2bf(v.w);
                int idx = r * 64 + (((c >> 1) ^ (r & 7)) << 3) + ((c & 1) << 2);
                *(ushort4v*)(&As[0][0] + idx) = o;
            }
        } else {
#pragma unroll
            for (int c = 0; c < 4; c++)
                gl_lds16(ga0 + k0 + (size_t)(32 * c) * K, lA + c * 2048);
        }
#pragma unroll
        for (int c = 0; c < 4; c++)
            gl_lds16(gb0 + k0 + (size_t)(32 * c) * K, lB + c * 2048);
        __syncthreads();

#pragma unroll
        for (int kk = 0; kk < 2; kk++) {
            const int gsw = ((kk * 4 + q) ^ (l16 & 7)) * 8;
            short8 a[4], b[4];
#pragma unroll
            for (int mt = 0; mt < 4; mt++)
                a[mt] = *(const short8*)(&As[0][0] + (wm * 64 + mt * 16 + l16) * 64 + gsw);
#pragma unroll
            for (int nt = 0; nt < 4; nt++)
                b[nt] = *(const short8*)(&Bs[0][0] + (wn * 64 + nt * 16 + l16) * 64 + gsw);
#pragma unroll
            for (int nt = 0; nt < 4; nt++)
#pragma unroll
                for (int mt = 0; mt < 4; mt++)
                    acc[nt][mt] = __builtin_amdgcn_mfma_f32_16x16x32_bf16(
                        b[nt], a[mt], acc[nt][mt], 0, 0, 0);
        }
        __syncthreads();
    }

    float rs4[4], mu4[4];
    if constexpr (EPMODE == 0) {
#pragma unroll
        for (int mt = 0; mt < 4; mt++) {
            const int row = m0 + wm * 64 + mt * 16 + l16;
            rs4[mt] = rs[row];
            mu4[mt] = mu[row];
        }
    }
#pragma unroll
    for (int nt = 0; nt < 4; nt++) {
        const int nbase = n0 + wn * 64 + nt * 16 + q * 4;
        const float4 bv = *(const float4*)(bias + nbase);
        float4 uv = {0.f, 0.f, 0.f, 0.f};
        if constexpr (EPMODE == 0) uv = *(const float4*)(u1 + nbase);
#pragma unroll
        for (int mt = 0; mt < 4; mt++) {
            const int row = m0 + wm * 64 + mt * 16 + l16;
            const size_t off = (size_t)row * N + nbase;
            float v0 = acc[nt][mt][0], v1 = acc[nt][mt][1];
            float v2 = acc[nt][mt][2], v3 = acc[nt][mt][3];
            if constexpr (EPMODE == 0) {
                v0 = gelu_fast(rs4[mt] * (v0 - mu4[mt] * uv.x) + bv.x);
                v1 = gelu_fast(rs4[mt] * (v1 - mu4[mt] * uv.y) + bv.y);
                v2 = gelu_fast(rs4[mt] * (v2 - mu4[mt] * uv.z) + bv.z);
                v3 = gelu_fast(rs4[mt] * (v3 - mu4[mt] * uv.w) + bv.w);
                uint2v o; o.x = pkbf(v0, v1); o.y = pkbf(v2, v3);
                *(uint2v*)((unsigned short*)Out + off) = o;
            } else if constexpr (EPMODE == 1) {
                v0 = gelu_fast(v0 + bv.x);
                v1 = gelu_fast(v1 + bv.y);
                v2 = gelu_fast(v2 + bv.z);
                v3 = gelu_fast(v3 + bv.w);
                uint2v o; o.x = pkbf(v0, v1); o.y = pkbf(v2, v3);
                *(uint2v*)((unsigned short*)Out + off) = o;
            } else if constexpr (EPMODE == 2) {
                const float4 rv = *(const float4*)((const float*)resid + off);
                float4 o;
                o.x = v0 + bv.x + rv.x;
                o.y = v1 + bv.y + rv.y;
                o.z = v2 + bv.z + rv.z;
                o.w = v3 + bv.w + rv.w;
                *(float4*)((float*)Out + off) = o;
            } else {
                const ushort4v rv =
                    *(const ushort4v*)((const unsigned short*)resid + off);
                float4 o;
                o.x = v0 + bv.x + bf2f(rv.x);
                o.y = v1 + bv.y + bf2f(rv.y);
                o.z = v2 + bv.z + bf2f(rv.z);
                o.w = v3 + bv.w + bf2f(rv.w);
                *(float4*)((float*)Out + off) = o;
            }
        }
    }
}

extern "C" void kernel_launch(void* const* d_in, const int* in_sizes, int n_in,
                              void* d_out, int out_size, void* d_ws, size_t ws_size,
                              hipStream_t stream) {
    const float* x     = (const float*)d_in[0];
    const float* gamma = (const float*)d_in[1];
    const float* beta  = (const float*)d_in[2];
    const float* W1    = (const float*)d_in[3];
    const float* b1    = (const float*)d_in[4];
    const float* W2    = (const float*)d_in[5];
    const float* b2    = (const float*)d_in[6];
    const float* W3    = (const float*)d_in[7];
    const float* b3    = (const float*)d_in[8];
    const float* W4    = (const float*)d_in[9];
    const float* b4    = (const float*)d_in[10];
    float* out = (float*)d_out;

    const int D = 1024, H1 = 512, H2 = 512;
    const int M = in_sizes[0] / D;   // 32768

    char* ws = (char*)d_ws;
    unsigned short* Wt1 = (unsigned short*)(ws + 0);
    unsigned short* Wt2 = (unsigned short*)(ws + 1048576);
    unsigned short* Wt3 = (unsigned short*)(ws + 1572864);
    unsigned short* Wt4 = (unsigned short*)(ws + 1835008);
    float* u1           = (float*)(ws + 2359296);
    float* c1           = (float*)(ws + 2361344);
    float* muv          = (float*)(ws + 2363392);
    float* rsv          = (float*)(ws + 2494464);
    unsigned short* h1  = (unsigned short*)(ws + 2625536);
    unsigned short* h2  = (unsigned short*)(ws + 36179968);
    unsigned short* h3  = h1;
    size_t base_end     = 36179968 + (size_t)M * H2 * 2;
    unsigned short* xb  = (unsigned short*)(ws + base_end);
    bool use_xb = (ws_size >= base_end + (size_t)M * D * 2);

    const int NBM = M / 128;   // 256

    conv_all_kernel<<<4608, 256, 0, stream>>>(W1, W2, W3, W4, gamma,
                                              Wt1, Wt2, Wt3, Wt4);
    u1c1_init_kernel<<<(H1 + 255) / 256, 256, 0, stream>>>(b1, u1, c1, H1);
    u1c1_kernel<<<D / 16, 256, 0, stream>>>(W1, gamma, beta, u1, c1);

    ln_stats_kernel<<<M / 4, 256, 0, stream>>>(x, muv, rsv, use_xb ? xb : nullptr);

    // ---- GEMM chain --------------------------------------------------------
    if (use_xb) {
        gemm256_kernel<0, 2, 16, 512, 1024><<<(M / 256) * 2, 512, 0, stream>>>(
            xb, Wt1, h1, c1, u1, muv, rsv);
    } else {
        gemm_kernel<0, true, 4, 512, 1024><<<4 * NBM, 256, 0, stream>>>(
            x, Wt1, h1, c1, u1, muv, rsv, nullptr);
    }
    gemm256_kernel<1, 2, 8, 512, 512><<<(M / 256) * 2, 512, 0, stream>>>(
        h1, Wt2, h2, b2, nullptr, nullptr, nullptr);
    gemm_kernel<1, false, 2, 256, 512><<<2 * NBM, 256, 0, stream>>>(
        h2, Wt3, h3, b3, nullptr, nullptr, nullptr, nullptr);
    if (use_xb) {
        gemm_kernel<3, false, 8, 1024, 256><<<8 * NBM, 256, 0, stream>>>(
            h3, Wt4, out, b4, nullptr, nullptr, nullptr, xb);
    } else {
        gemm_kernel<2, false, 8, 1024, 256><<<8 * NBM, 256, 0, stream>>>(
            h3, Wt4, out, b4, nullptr, nullptr, nullptr, x);
    }
}